// Round 10
// baseline (878.857 us; speedup 1.0000x reference)
//
#include <hip/hip_runtime.h>
#include <hip/hip_bf16.h>

// Problem constants (B=1)
#define N_TOK 8192
#define DIM   1024
#define NEXP  8
#define FF    4096
#define CAP   2560            // int(8192*2*1.25/8)
#define NASSIGN (N_TOK * 2)   // K=2, slot-major: j = s*N + t
#define FFD   ((size_t)FF * DIM)            // 4,194,304 elems (2^22)
#define CAPD  ((size_t)CAP * DIM)           // 2,621,440 elems
#define CH    (2 * FFD + CAPD)              // per-expert chunk: Wg|Wu|Xe = 11,010,048
// eo(e) = 4 split-K slices x CAPD = 10,485,760 elems <= CH, aliased onto chunk(e).
// Safe under fusion: chunk(e) is read ONLY by expert e's gateup (32 blocks),
// all of which signal flag[e] before any of them starts down(e)'s writes.

typedef __bf16 bf16;
typedef __bf16 bf16x8 __attribute__((ext_vector_type(8)));
typedef __bf16 bf16x4v __attribute__((ext_vector_type(4)));
typedef float  f32x4  __attribute__((ext_vector_type(4)));

// async global->LDS DMA, 16B per lane. LDS dest = wave-uniform base + lane*16.
__device__ __forceinline__ void gl2lds16(const bf16* g, bf16* l) {
    __builtin_amdgcn_global_load_lds(
        (const __attribute__((address_space(1))) unsigned int*)g,
        (__attribute__((address_space(3))) unsigned int*)l,
        16, 0, 0);
}

// ---------------------------------------------------------------------------
// PERSISTENT 256x256x64 GEMM core (2ph schedule, r7-r9 validated inner tile).
// LDS passed in (shared between the two fused phases). Per tile:
// STAGE(next, other buf) -> ds_read B(8)+A(2x8) -> setprio'd MFMA -> vmcnt(0)
// -> ONE s_barrier. Cross-unit: last tile stages next unit's tile 0 (NT even
// -> lands in buf0). Swizzle involution: source chunk (lane&7)^(lane>>3);
// read phys chunk (kk*4+c16)^(lds_row&7).
// ---------------------------------------------------------------------------
template <int NT, int AST, int BST, int BG1, int BG2, class UnitFn, class EpiFn>
__device__ __forceinline__ void gemm256_persist(
    int nunits, UnitFn unit, EpiFn epi, int wave, int lane, bf16* As, bf16* Bs)
{
    const int wm = wave >> 2, wn = wave & 3;
    const int r16 = lane & 15, c16 = lane >> 4;
    const int wbase = wave * 8 * 64;

    auto STAGE = [&](const bf16* a, const bf16* bb, int buf) {
#pragma unroll
        for (int g = 0; g < 4; ++g)
            gl2lds16(a + (size_t)g * 64 * AST,
                     &As[buf * (256 * 64) + g * (64 * 64) + wbase]);
#pragma unroll
        for (int g = 0; g < 4; ++g)
            gl2lds16(bb + (size_t)((g & 1) * BG1 + (g >> 1) * BG2) * BST,
                     &Bs[buf * (256 * 64) + g * (64 * 64) + wbase]);
    };

    const bf16 *pA, *pB;
    unit(0, pA, pB);
    STAGE(pA, pB, 0);
    asm volatile("s_waitcnt vmcnt(0)" ::: "memory");
    __builtin_amdgcn_sched_barrier(0);
    __builtin_amdgcn_s_barrier();
    __builtin_amdgcn_sched_barrier(0);

    for (int u = 0; u < nunits; ++u) {
        const bf16 *pAn = pA, *pBn = pB;
        const bool more = (u + 1 < nunits);
        if (more) unit(u + 1, pAn, pBn);

        f32x4 acc[8][4] = {};
        for (int kt = 0; kt < NT; ++kt) {
            if (kt + 1 < NT)
                STAGE(pA + (size_t)(kt + 1) * 64, pB + (size_t)(kt + 1) * 64, (kt + 1) & 1);
            else if (more)
                STAGE(pAn, pBn, 0);

            const bf16* Asb = &As[(kt & 1) * (256 * 64)];
            const bf16* Bsb = &Bs[(kt & 1) * (256 * 64)];

            bf16x8 bfr[4][2];
#pragma unroll
            for (int nh = 0; nh < 2; ++nh)
#pragma unroll
                for (int np = 0; np < 2; ++np)
#pragma unroll
                    for (int kk = 0; kk < 2; ++kk) {
                        int rl = nh * 128 + wn * 32 + np * 16 + r16;
                        int phys = (kk * 4 + c16) ^ (rl & 7);
                        bfr[nh * 2 + np][kk] = *(const bf16x8*)&Bsb[rl * 64 + phys * 8];
                    }
#pragma unroll
            for (int mh = 0; mh < 2; ++mh) {
                bf16x8 af[4][2];
#pragma unroll
                for (int mm = 0; mm < 4; ++mm)
#pragma unroll
                    for (int kk = 0; kk < 2; ++kk) {
                        int row = wm * 128 + mh * 64 + mm * 16 + r16;
                        int phys = (kk * 4 + c16) ^ (row & 7);
                        af[mm][kk] = *(const bf16x8*)&Asb[row * 64 + phys * 8];
                    }
                __builtin_amdgcn_s_setprio(1);
#pragma unroll
                for (int mm = 0; mm < 4; ++mm)
#pragma unroll
                    for (int nf = 0; nf < 4; ++nf)
#pragma unroll
                        for (int kk = 0; kk < 2; ++kk)
                            acc[mh * 4 + mm][nf] =
                                __builtin_amdgcn_mfma_f32_16x16x32_bf16(
                                    af[mm][kk], bfr[nf][kk], acc[mh * 4 + mm][nf], 0, 0, 0);
                __builtin_amdgcn_s_setprio(0);
            }

            asm volatile("s_waitcnt vmcnt(0)" ::: "memory");
            __builtin_amdgcn_sched_barrier(0);
            __builtin_amdgcn_s_barrier();
            __builtin_amdgcn_sched_barrier(0);
        }
        epi(u, acc);
        pA = pAn; pB = pBn;
    }
}

// ---------------------------------------------------------------------------
// prep: cvt (Wg/Wu -> per-expert chunks, Wd -> flat bf16) + router, one launch.
// Blocks [0,3072): cvt (1024 per tensor); [3072,5120): router (4 tokens each).
// ---------------------------------------------------------------------------
__global__ __launch_bounds__(256) void prep_kernel(const float* __restrict__ Wg,
                                                   const float* __restrict__ Wu,
                                                   const float* __restrict__ Wd,
                                                   bf16* __restrict__ chunks,
                                                   bf16* __restrict__ Wd_bf,
                                                   const float* __restrict__ x,
                                                   const float* __restrict__ Wr,
                                                   float* __restrict__ probs,
                                                   int* __restrict__ topi,
                                                   float* __restrict__ topw) {
    if (blockIdx.x < 3072) {
        const int which = blockIdx.x >> 10;
        const int bx = blockIdx.x & 1023;
        const float* in = (which == 0) ? Wg : (which == 1) ? Wu : Wd;
        const int n = NEXP * (int)FFD;
        const int stride = 1024 * 256 * 8;
        for (int i = (bx * 256 + threadIdx.x) * 8; i < n; i += stride) {
            float4 a = *(const float4*)(in + i);
            float4 b = *(const float4*)(in + i + 4);
            bf16x8 o;
            o[0] = (bf16)a.x; o[1] = (bf16)a.y; o[2] = (bf16)a.z; o[3] = (bf16)a.w;
            o[4] = (bf16)b.x; o[5] = (bf16)b.y; o[6] = (bf16)b.z; o[7] = (bf16)b.w;
            if (which == 2) {
                *(bf16x8*)(Wd_bf + i) = o;
            } else {
                int e = i >> 22;                       // FFD = 2^22
                size_t rem = (size_t)(i & ((1 << 22) - 1));
                *(bf16x8*)(chunks + (size_t)e * CH + (which ? FFD : 0) + rem) = o;
            }
        }
        return;
    }
    // ---- router: fp64 logits, softmax, top-2 ----
    int wave = threadIdx.x >> 6;
    int lane = threadIdx.x & 63;
    int t = (blockIdx.x - 3072) * 4 + wave;
    const float* xr = x + (size_t)t * DIM;

    double acc[NEXP];
#pragma unroll
    for (int e = 0; e < NEXP; ++e) acc[e] = 0.0;
    for (int i = lane; i < DIM; i += 64) {
        double xv = (double)xr[i];
#pragma unroll
        for (int e = 0; e < NEXP; ++e) acc[e] += xv * (double)Wr[e * DIM + i];
    }
#pragma unroll
    for (int e = 0; e < NEXP; ++e) {
        double v = acc[e];
        for (int off = 32; off > 0; off >>= 1) v += __shfl_down(v, off, 64);
        acc[e] = v;
    }
    if (lane == 0) {
        double mx = acc[0];
        for (int e = 1; e < NEXP; ++e) if (acc[e] > mx) mx = acc[e];
        double p[NEXP], s = 0.0;
        for (int e = 0; e < NEXP; ++e) { p[e] = exp(acc[e] - mx); s += p[e]; }
        float pf[NEXP];
        for (int e = 0; e < NEXP; ++e) { pf[e] = (float)(p[e] / s); probs[t * NEXP + e] = pf[e]; }
        int e1 = 0;
        for (int e = 1; e < NEXP; ++e) if (acc[e] > acc[e1]) e1 = e;
        int e2 = -1;
        for (int e = 0; e < NEXP; ++e) {
            if (e == e1) continue;
            if (e2 < 0 || acc[e] > acc[e2]) e2 = e;
        }
        float w1 = pf[e1], w2 = pf[e2];
        float inv = 1.0f / (w1 + w2 + 1e-9f);
        topi[t * 2 + 0] = e1; topi[t * 2 + 1] = e2;
        topw[t * 2 + 0] = w1 * inv; topw[t * 2 + 1] = w2 * inv;
    }
}

// ---------------------------------------------------------------------------
// Rank/capacity in exact slot-major reference order. One wave per expert.
// ---------------------------------------------------------------------------
__global__ __launch_bounds__(64) void rank_kernel(const int* __restrict__ topi,
                                                  int* __restrict__ dest,
                                                  int* __restrict__ accf,
                                                  int* __restrict__ counts) {
    int e = blockIdx.x;
    int lane = threadIdx.x;
    const int per = NASSIGN / 64;  // 256
    int base = lane * per;
    int cnt = 0;
    for (int i = 0; i < per; ++i) {
        int j = base + i;
        int t = j & (N_TOK - 1), s = j >> 13;
        if (topi[t * 2 + s] == e) cnt++;
    }
    int sum = cnt;
    for (int off = 1; off < 64; off <<= 1) {
        int v = __shfl_up(sum, off, 64);
        if (lane >= off) sum += v;
    }
    int r = sum - cnt;                       // exclusive prefix
    int total = __shfl(sum, 63, 64);
    for (int i = 0; i < per; ++i) {
        int j = base + i;
        int t = j & (N_TOK - 1), s = j >> 13;
        if (topi[t * 2 + s] == e) {
            int acc = (r < CAP) ? 1 : 0;
            dest[j] = e * CAP + (acc ? r : 0);
            accf[j] = acc;
            r++;
        }
    }
    if (lane == 63) counts[e] = (total < CAP) ? total : CAP;
}

// ---------------------------------------------------------------------------
// Gather: x row -> bf16 Xe row inside expert chunk. One block per assignment.
// ---------------------------------------------------------------------------
__global__ __launch_bounds__(256) void gather_kernel(const float* __restrict__ x,
                                                     const int* __restrict__ dest,
                                                     const int* __restrict__ accf,
                                                     bf16* __restrict__ chunks) {
    int j = blockIdx.x;
    if (!accf[j]) return;
    int t = j & (N_TOK - 1);
    int d = dest[j];
    int e = d / CAP, rr = d - e * CAP;
    int d0 = threadIdx.x * 4;
    float4 v = *(const float4*)(x + (size_t)t * DIM + d0);
    union { bf16 h[4]; uint2 u; } tmp;
    tmp.h[0] = (bf16)v.x; tmp.h[1] = (bf16)v.y; tmp.h[2] = (bf16)v.z; tmp.h[3] = (bf16)v.w;
    *(uint2*)(chunks + (size_t)e * CH + 2 * FFD + (size_t)rr * DIM + d0) = tmp.u;
}

// ---------------------------------------------------------------------------
// Fused FFN: gateup (10 units) -> per-expert release/acquire barrier ->
// down (5 units, split-K=4). Grid 256 = 1 block/CU (co-resident), e = b&7.
// Gateup: unit g=u*32+r -> n=g/10, m=g%10; B = interleaved {gate,up} cols.
// Down: mk=u*8+(r&7) -> m=mk>>2, kh=mk&3; n=r>>3; bf16 partials into
// eo(e) = chunk(e) + kh*CAPD (alias safe: see CH comment).
// Barrier: all 32 blocks of expert e signal flag[e] (agent-release) after
// their last chunk(e)/hbuf ops; spin agent-acquire until 32 -> down.
// ---------------------------------------------------------------------------
__global__ __launch_bounds__(512, 2) void ffn_kernel(bf16* __restrict__ chunks,
                                                     const bf16* __restrict__ Wd_bf,
                                                     bf16* __restrict__ hbuf,
                                                     int* __restrict__ flags) {
    __shared__ bf16 As[2 * 256 * 64];
    __shared__ bf16 Bs[2 * 256 * 64];

    const int b = blockIdx.x;
    const int e = b & 7, r = b >> 3;
    const int tid = threadIdx.x, lane = tid & 63, wave = tid >> 6;
    const int wm = wave >> 2, wn = wave & 3;
    const int r16 = lane & 15, c16 = lane >> 4;

    const int l   = wave * 8 + (lane >> 3);
    const int csw = ((lane & 7) ^ (lane >> 3)) * 8;

    // ---- phase 1: gateup ----
    {
        const int T = (l >> 4) & 1, wnl = l >> 5, r16l = l & 15;
        const bf16* XeE = chunks + (size_t)e * CH + 2 * FFD + (size_t)l * DIM + csw;
        const bf16* WE  = chunks + (size_t)e * CH + (T ? FFD : 0)
                        + (size_t)(wnl * 32 + r16l) * DIM + csw;
        bf16* hp = hbuf + (size_t)e * CAP * FF;

        auto unit = [&](int u, const bf16*& pA, const bf16*& pB) {
            int g = u * 32 + r;
            int m = g % 10, n = g / 10;
            pA = XeE + (size_t)(m * 256) * DIM;
            pB = WE + (size_t)(n * 128) * DIM;
        };
        auto epi = [&](int u, f32x4 (&acc)[8][4]) {
            int g = u * 32 + r;
            int m0 = (g % 10) * 256, n0f = (g / 10) * 128;
#pragma unroll
            for (int m = 0; m < 8; ++m)
#pragma unroll
                for (int cg = 0; cg < 2; ++cg)
#pragma unroll
                    for (int j = 0; j < 4; ++j) {
                        float gg = acc[m][cg * 2 + 0][j];
                        float uu = acc[m][cg * 2 + 1][j];
                        float h = (gg / (1.f + __expf(-gg))) * uu;
                        int gr = m0 + wm * 128 + m * 16 + c16 * 4 + j;
                        int gc = n0f + wn * 32 + cg * 16 + r16;
                        hp[(size_t)gr * FF + gc] = (bf16)h;
                    }
        };
        gemm256_persist<DIM / 64, DIM, DIM, 64, 16>(10, unit, epi, wave, lane, As, Bs);
    }

    // ---- per-expert device barrier (agent scope: handles cross-XCD L2) ----
    __syncthreads();   // all waves' epi stores retired (vmcnt drained) on this CU
    if (tid == 0) {
        __hip_atomic_fetch_add(&flags[e], 1, __ATOMIC_RELEASE, __HIP_MEMORY_SCOPE_AGENT);
        while (__hip_atomic_load(&flags[e], __ATOMIC_ACQUIRE, __HIP_MEMORY_SCOPE_AGENT) < 32) {}
        __threadfence();   // belt-and-suspenders acquire (wb+inv)
    }
    __syncthreads();

    // ---- phase 2: down ----
    {
        const int nlow = (l >> 4) & 1, wnl = l >> 5, r16l = l & 15;
        const bf16* hb  = hbuf + (size_t)e * CAP * FF + (size_t)l * FF + csw;
        const bf16* WdE = Wd_bf + (size_t)e * DIM * FF
                        + (size_t)(wnl * 64 + nlow * 16 + r16l) * FF + csw;
        bf16* eoE = chunks + (size_t)e * CH;   // 4 slices of CAPD each

        auto unit = [&](int u, const bf16*& pA, const bf16*& pB) {
            int mk = u * 8 + (r & 7);
            int n  = r >> 3;
            int m = mk >> 2, kh = mk & 3;
            pA = hb + (size_t)(m * 256) * FF + kh * (FF / 4);
            pB = WdE + (size_t)(n * 256) * FF + kh * (FF / 4);
        };
        auto epi = [&](int u, f32x4 (&acc)[8][4]) {
            int mk = u * 8 + (r & 7);
            int m0 = (mk >> 2) * 256, kh = mk & 3;
            int n0 = (r >> 3) * 256;
            bf16* op = eoE + (size_t)kh * CAPD;
#pragma unroll
            for (int m = 0; m < 8; ++m)
#pragma unroll
                for (int nf = 0; nf < 4; ++nf)
#pragma unroll
                    for (int j = 0; j < 4; ++j) {
                        int gr = m0 + wm * 128 + m * 16 + c16 * 4 + j;
                        int gc = n0 + wn * 64 + nf * 16 + r16;
                        op[(size_t)gr * DIM + gc] = (bf16)acc[m][nf][j];
                    }
        };
        gemm256_persist<(FF / 4) / 64, FF, FF, 128, 32>(5, unit, epi, wave, lane, As, Bs);
    }
}

// ---------------------------------------------------------------------------
// Combine: out[t] = sum_s w_ts * acc_ts * sum_{kh<4} eo(e_ts)[kh][row_ts].
// ---------------------------------------------------------------------------
__global__ __launch_bounds__(256) void combine_kernel(const bf16* __restrict__ chunks,
                                                      const int* __restrict__ dest,
                                                      const int* __restrict__ accf,
                                                      const float* __restrict__ topw,
                                                      float* __restrict__ out) {
    int t = blockIdx.x;
    float w0 = accf[t] ? topw[t * 2 + 0] : 0.f;           // slot 0: j = t
    float w1 = accf[N_TOK + t] ? topw[t * 2 + 1] : 0.f;   // slot 1: j = N + t
    int d0a = dest[t], d0b = dest[N_TOK + t];
    int ea = d0a / CAP, ra = d0a - ea * CAP;
    int eb = d0b / CAP, rb = d0b - eb * CAP;
    const bf16* a0 = chunks + (size_t)ea * CH + (size_t)ra * DIM;
    const bf16* b0 = chunks + (size_t)eb * CH + (size_t)rb * DIM;
    int d = threadIdx.x * 4;
    float ax = 0, ay = 0, az = 0, aw = 0, bx = 0, by = 0, bz = 0, bw = 0;
#pragma unroll
    for (int s4 = 0; s4 < 4; ++s4) {
        bf16x4v a = *(const bf16x4v*)(a0 + (size_t)s4 * CAPD + d);
        bf16x4v bb = *(const bf16x4v*)(b0 + (size_t)s4 * CAPD + d);
        ax += (float)a[0]; ay += (float)a[1]; az += (float)a[2]; aw += (float)a[3];
        bx += (float)bb[0]; by += (float)bb[1]; bz += (float)bb[2]; bw += (float)bb[3];
    }
    float4 o;
    o.x = w0 * ax + w1 * bx;
    o.y = w0 * ay + w1 * by;
    o.z = w0 * az + w1 * bz;
    o.w = w0 * aw + w1 * bw;
    *(float4*)(out + (size_t)t * DIM + d) = o;
}

// ---------------------------------------------------------------------------
// Aux loss: deterministic fixed-tree reduction of probs mean + counts.
// ---------------------------------------------------------------------------
__global__ __launch_bounds__(256) void aux_kernel(const float* __restrict__ probs,
                                                  const int* __restrict__ counts,
                                                  float* __restrict__ out_aux) {
    __shared__ float sm[256][NEXP];
    float loc[NEXP];
#pragma unroll
    for (int e = 0; e < NEXP; ++e) loc[e] = 0.f;
    for (int t = threadIdx.x; t < N_TOK; t += 256)
#pragma unroll
        for (int e = 0; e < NEXP; ++e) loc[e] += probs[t * NEXP + e];
#pragma unroll
    for (int e = 0; e < NEXP; ++e) sm[threadIdx.x][e] = loc[e];
    __syncthreads();
    for (int s = 128; s > 0; s >>= 1) {
        if (threadIdx.x < s)
#pragma unroll
            for (int e = 0; e < NEXP; ++e) sm[threadIdx.x][e] += sm[threadIdx.x + s][e];
        __syncthreads();
    }
    if (threadIdx.x == 0) {
        int tot = 0;
        for (int e = 0; e < NEXP; ++e) tot += counts[e];
        float totf = tot > 0 ? (float)tot : 1.f;
        float aux = 0.f;
        for (int e = 0; e < NEXP; ++e)
            aux += ((float)counts[e] / totf) * (sm[0][e] / (float)N_TOK);
        out_aux[0] = 0.01f * (float)NEXP * aux;
    }
}

// ---------------------------------------------------------------------------
extern "C" void kernel_launch(void* const* d_in, const int* in_sizes, int n_in,
                              void* d_out, int out_size, void* d_ws, size_t ws_size,
                              hipStream_t stream) {
    const float* x  = (const float*)d_in[0];
    const float* Wr = (const float*)d_in[1];
    const float* Wg = (const float*)d_in[2];
    const float* Wu = (const float*)d_in[3];
    const float* Wd = (const float*)d_in[4];
    float* out = (float*)d_out;

    char* ws = (char*)d_ws;
    size_t off = 0;
    auto alloc = [&](size_t bytes) -> void* {
        void* p = ws + off;
        off += (bytes + 255) & ~(size_t)255;
        return p;
    };
    const size_t NW = (size_t)NEXP * FFD;
    bf16*  chunks = (bf16*)alloc((size_t)NEXP * CH * sizeof(bf16)); // [Wg_e|Wu_e|Xe_e] x8, eo aliased
    bf16*  Wd_bf  = (bf16*)alloc(NW * sizeof(bf16));
    bf16*  hbuf   = (bf16*)alloc((size_t)NEXP * CAP * FF * sizeof(bf16));
    float* probs  = (float*)alloc((size_t)N_TOK * NEXP * sizeof(float));
    int*   topi   = (int*)alloc((size_t)N_TOK * 2 * sizeof(int));
    float* topw   = (float*)alloc((size_t)N_TOK * 2 * sizeof(float));
    int*   dst    = (int*)alloc((size_t)NASSIGN * sizeof(int));
    int*   accf   = (int*)alloc((size_t)NASSIGN * sizeof(int));
    int*   cnts   = (int*)alloc(NEXP * sizeof(int));
    int*   flags  = (int*)alloc(NEXP * sizeof(int));

    hipMemsetAsync(flags, 0, NEXP * sizeof(int), stream);
    prep_kernel<<<5120, 256, 0, stream>>>(Wg, Wu, Wd, chunks, Wd_bf, x, Wr, probs, topi, topw);
    rank_kernel<<<NEXP, 64, 0, stream>>>(topi, dst, accf, cnts);
    gather_kernel<<<NASSIGN, 256, 0, stream>>>(x, dst, accf, chunks);
    ffn_kernel<<<256, 512, 0, stream>>>(chunks, Wd_bf, hbuf, flags);
    combine_kernel<<<N_TOK, 256, 0, stream>>>(chunks, dst, accf, topw, out);
    aux_kernel<<<1, 256, 0, stream>>>(probs, cnts, out + (size_t)N_TOK * DIM);
}

// Round 11
// 829.702 us; speedup vs baseline: 1.0592x; 1.0592x over previous
//
#include <hip/hip_runtime.h>
#include <hip/hip_bf16.h>

// Problem constants (B=1)
#define N_TOK 8192
#define DIM   1024
#define NEXP  8
#define FF    4096
#define CAP   2560            // int(8192*2*1.25/8)
#define NASSIGN (N_TOK * 2)   // K=2, slot-major: j = s*N + t
#define EOSL  ((size_t)NEXP * CAP * DIM)   // one split-K eo slice (elems)

typedef __bf16 bf16;
typedef __bf16 bf16x8 __attribute__((ext_vector_type(8)));
typedef __bf16 bf16x4v __attribute__((ext_vector_type(4)));
typedef float  f32x4  __attribute__((ext_vector_type(4)));

// async global->LDS DMA, 16B per lane. LDS dest = wave-uniform base + lane*16.
__device__ __forceinline__ void gl2lds16(const bf16* g, bf16* l) {
    __builtin_amdgcn_global_load_lds(
        (const __attribute__((address_space(1))) unsigned int*)g,
        (__attribute__((address_space(3))) unsigned int*)l,
        16, 0, 0);
}

// ---------------------------------------------------------------------------
// PERSISTENT 256x256x64 GEMM core (2ph schedule, r7/r8-validated inner tile).
// One block per CU runs `nunits` units through a single warm pipeline:
// tile stream is flat; at a unit's last tile we stage the NEXT unit's tile 0
// (NT even -> cross-unit stage lands in buf0 = next unit's kt=0 buffer).
// Per tile: STAGE(next, other buf) -> ds_read B(8)+A(2x8) -> setprio'd MFMA
// clusters -> vmcnt(0) -> ONE s_barrier. Hazards validated in r7/r8.
// Swizzle involution: source chunk (lane&7)^(lane>>3); read phys chunk
// (kk*4+c16)^(lds_row&7); lds_row&7 == lane>>3 on the staged side.
// ---------------------------------------------------------------------------
template <int NT, int AST, int BST, int BG1, int BG2, class UnitFn, class EpiFn>
__device__ __forceinline__ void gemm256_persist(
    int nunits, UnitFn unit, EpiFn epi, int wave, int lane)
{
    __shared__ bf16 As[2 * 256 * 64];
    __shared__ bf16 Bs[2 * 256 * 64];

    const int wm = wave >> 2, wn = wave & 3;
    const int r16 = lane & 15, c16 = lane >> 4;
    const int wbase = wave * 8 * 64;   // wave's 8-row slice inside a 64-row group

    auto STAGE = [&](const bf16* a, const bf16* bb, int buf) {
#pragma unroll
        for (int g = 0; g < 4; ++g)
            gl2lds16(a + (size_t)g * 64 * AST,
                     &As[buf * (256 * 64) + g * (64 * 64) + wbase]);
#pragma unroll
        for (int g = 0; g < 4; ++g)
            gl2lds16(bb + (size_t)((g & 1) * BG1 + (g >> 1) * BG2) * BST,
                     &Bs[buf * (256 * 64) + g * (64 * 64) + wbase]);
    };

    const bf16 *pA, *pB;
    unit(0, pA, pB);
    STAGE(pA, pB, 0);
    asm volatile("s_waitcnt vmcnt(0)" ::: "memory");
    __builtin_amdgcn_sched_barrier(0);
    __builtin_amdgcn_s_barrier();
    __builtin_amdgcn_sched_barrier(0);

    for (int u = 0; u < nunits; ++u) {
        const bf16 *pAn = pA, *pBn = pB;
        const bool more = (u + 1 < nunits);
        if (more) unit(u + 1, pAn, pBn);

        f32x4 acc[8][4] = {};
        for (int kt = 0; kt < NT; ++kt) {
            if (kt + 1 < NT)
                STAGE(pA + (size_t)(kt + 1) * 64, pB + (size_t)(kt + 1) * 64, (kt + 1) & 1);
            else if (more)
                STAGE(pAn, pBn, 0);   // NT even -> buf0 = next unit's kt=0 buffer

            const bf16* Asb = &As[(kt & 1) * (256 * 64)];
            const bf16* Bsb = &Bs[(kt & 1) * (256 * 64)];

            bf16x8 bfr[4][2];
#pragma unroll
            for (int nh = 0; nh < 2; ++nh)
#pragma unroll
                for (int np = 0; np < 2; ++np)
#pragma unroll
                    for (int kk = 0; kk < 2; ++kk) {
                        int rl = nh * 128 + wn * 32 + np * 16 + r16;
                        int phys = (kk * 4 + c16) ^ (rl & 7);
                        bfr[nh * 2 + np][kk] = *(const bf16x8*)&Bsb[rl * 64 + phys * 8];
                    }
#pragma unroll
            for (int mh = 0; mh < 2; ++mh) {
                bf16x8 af[4][2];
#pragma unroll
                for (int mm = 0; mm < 4; ++mm)
#pragma unroll
                    for (int kk = 0; kk < 2; ++kk) {
                        int row = wm * 128 + mh * 64 + mm * 16 + r16;
                        int phys = (kk * 4 + c16) ^ (row & 7);
                        af[mm][kk] = *(const bf16x8*)&Asb[row * 64 + phys * 8];
                    }
                __builtin_amdgcn_s_setprio(1);
#pragma unroll
                for (int mm = 0; mm < 4; ++mm)
#pragma unroll
                    for (int nf = 0; nf < 4; ++nf)
#pragma unroll
                        for (int kk = 0; kk < 2; ++kk)
                            acc[mh * 4 + mm][nf] =
                                __builtin_amdgcn_mfma_f32_16x16x32_bf16(
                                    af[mm][kk], bfr[nf][kk], acc[mh * 4 + mm][nf], 0, 0, 0);
                __builtin_amdgcn_s_setprio(0);
            }

            asm volatile("s_waitcnt vmcnt(0)" ::: "memory");
            __builtin_amdgcn_sched_barrier(0);
            __builtin_amdgcn_s_barrier();
            __builtin_amdgcn_sched_barrier(0);
        }
        epi(u, acc);
        pA = pAn; pB = pBn;
    }
}

// ---------------------------------------------------------------------------
// fp32 -> bf16 weight conversion: one launch for all three tensors
// (blockIdx.y selects tensor; grid-stride within).
// ---------------------------------------------------------------------------
__global__ __launch_bounds__(256) void cvt3_bf16_kernel(const float* __restrict__ a,
                                                        const float* __restrict__ b,
                                                        const float* __restrict__ c,
                                                        bf16* __restrict__ oa,
                                                        bf16* __restrict__ ob,
                                                        bf16* __restrict__ oc, int n) {
    const float* in = (blockIdx.y == 0) ? a : (blockIdx.y == 1) ? b : c;
    bf16*       out = (blockIdx.y == 0) ? oa : (blockIdx.y == 1) ? ob : oc;
    int stride = gridDim.x * blockDim.x * 8;
    for (int i = (blockIdx.x * blockDim.x + threadIdx.x) * 8; i < n; i += stride) {
        float4 x = *(const float4*)(in + i);
        float4 y = *(const float4*)(in + i + 4);
        bf16x8 o;
        o[0] = (bf16)x.x; o[1] = (bf16)x.y; o[2] = (bf16)x.z; o[3] = (bf16)x.w;
        o[4] = (bf16)y.x; o[5] = (bf16)y.y; o[6] = (bf16)y.z; o[7] = (bf16)y.w;
        *(bf16x8*)(out + i) = o;
    }
}

// ---------------------------------------------------------------------------
// Router: logits in fp64 (top-k selection robustness), softmax, top-2.
// ---------------------------------------------------------------------------
__global__ __launch_bounds__(256) void router_kernel(const float* __restrict__ x,
                                                     const float* __restrict__ Wr,
                                                     float* __restrict__ probs,
                                                     int* __restrict__ topi,
                                                     float* __restrict__ topw) {
    int wave = threadIdx.x >> 6;
    int lane = threadIdx.x & 63;
    int t = blockIdx.x * 4 + wave;
    const float* xr = x + (size_t)t * DIM;

    double acc[NEXP];
#pragma unroll
    for (int e = 0; e < NEXP; ++e) acc[e] = 0.0;
    for (int i = lane; i < DIM; i += 64) {
        double xv = (double)xr[i];
#pragma unroll
        for (int e = 0; e < NEXP; ++e) acc[e] += xv * (double)Wr[e * DIM + i];
    }
#pragma unroll
    for (int e = 0; e < NEXP; ++e) {
        double v = acc[e];
        for (int off = 32; off > 0; off >>= 1) v += __shfl_down(v, off, 64);
        acc[e] = v;  // valid on lane 0
    }
    if (lane == 0) {
        double mx = acc[0];
        for (int e = 1; e < NEXP; ++e) if (acc[e] > mx) mx = acc[e];
        double p[NEXP], s = 0.0;
        for (int e = 0; e < NEXP; ++e) { p[e] = exp(acc[e] - mx); s += p[e]; }
        float pf[NEXP];
        for (int e = 0; e < NEXP; ++e) { pf[e] = (float)(p[e] / s); probs[t * NEXP + e] = pf[e]; }
        int e1 = 0;
        for (int e = 1; e < NEXP; ++e) if (acc[e] > acc[e1]) e1 = e;
        int e2 = -1;
        for (int e = 0; e < NEXP; ++e) {
            if (e == e1) continue;
            if (e2 < 0 || acc[e] > acc[e2]) e2 = e;
        }
        float w1 = pf[e1], w2 = pf[e2];
        float inv = 1.0f / (w1 + w2 + 1e-9f);
        topi[t * 2 + 0] = e1; topi[t * 2 + 1] = e2;
        topw[t * 2 + 0] = w1 * inv; topw[t * 2 + 1] = w2 * inv;
    }
}

// ---------------------------------------------------------------------------
// Rank/capacity in exact slot-major reference order. One wave per expert.
// ---------------------------------------------------------------------------
__global__ __launch_bounds__(64) void rank_kernel(const int* __restrict__ topi,
                                                  int* __restrict__ dest,
                                                  int* __restrict__ accf,
                                                  int* __restrict__ counts) {
    int e = blockIdx.x;
    int lane = threadIdx.x;
    const int per = NASSIGN / 64;  // 256
    int base = lane * per;
    int cnt = 0;
    for (int i = 0; i < per; ++i) {
        int j = base + i;
        int t = j & (N_TOK - 1), s = j >> 13;
        if (topi[t * 2 + s] == e) cnt++;
    }
    int sum = cnt;
    for (int off = 1; off < 64; off <<= 1) {
        int v = __shfl_up(sum, off, 64);
        if (lane >= off) sum += v;
    }
    int r = sum - cnt;                       // exclusive prefix
    int total = __shfl(sum, 63, 64);
    for (int i = 0; i < per; ++i) {
        int j = base + i;
        int t = j & (N_TOK - 1), s = j >> 13;
        if (topi[t * 2 + s] == e) {
            int acc = (r < CAP) ? 1 : 0;
            dest[j] = e * CAP + (acc ? r : 0);
            accf[j] = acc;
            r++;
        }
    }
    if (lane == 63) counts[e] = (total < CAP) ? total : CAP;
}

// ---------------------------------------------------------------------------
// Gather: x row -> bf16 capacity buffer row. One block per assignment.
// ---------------------------------------------------------------------------
__global__ __launch_bounds__(256) void gather_kernel(const float* __restrict__ x,
                                                     const int* __restrict__ dest,
                                                     const int* __restrict__ accf,
                                                     bf16* __restrict__ Xe) {
    int j = blockIdx.x;
    if (!accf[j]) return;
    int t = j & (N_TOK - 1);
    int d0 = threadIdx.x * 4;
    float4 v = *(const float4*)(x + (size_t)t * DIM + d0);
    union { bf16 h[4]; uint2 u; } tmp;
    tmp.h[0] = (bf16)v.x; tmp.h[1] = (bf16)v.y; tmp.h[2] = (bf16)v.z; tmp.h[3] = (bf16)v.w;
    *(uint2*)(Xe + (size_t)dest[j] * DIM + d0) = tmp.u;
}

// ---------------------------------------------------------------------------
// gateup (persistent): grid 256, block b -> expert e=b&7 (XCD-affine under rr
// dispatch), r=b>>3 in [0,32). Unit u in [0,10): g=u*32+r -> n=g/10, m=g%10.
// BN=256 interleaved cols = 128 FF cols x {gate,up}; B col decomposition
// validated r6-r8: T=(l>>4)&1 picks tensor, col = wnl*32 + r16l (+unit n0f).
// ---------------------------------------------------------------------------
__global__ __launch_bounds__(512, 2) void gateup_kernel(const bf16* __restrict__ Xe,
                                                        const bf16* __restrict__ Wg,
                                                        const bf16* __restrict__ Wu,
                                                        bf16* __restrict__ hbuf) {
    const int b = blockIdx.x;
    const int e = b & 7, r = b >> 3;
    const int tid = threadIdx.x, lane = tid & 63, wave = tid >> 6;
    const int wm = wave >> 2, wn = wave & 3;
    const int r16 = lane & 15, c16 = lane >> 4;

    const int l   = wave * 8 + (lane >> 3);
    const int csw = ((lane & 7) ^ (lane >> 3)) * 8;
    const int T = (l >> 4) & 1, wnl = l >> 5, r16l = l & 15;
    const bf16* XeE = Xe + (size_t)e * CAP * DIM + (size_t)l * DIM + csw;
    const bf16* WE  = (T ? Wu : Wg) + (size_t)e * FF * DIM
                    + (size_t)(wnl * 32 + r16l) * DIM + csw;
    bf16* hp = hbuf + (size_t)e * CAP * FF;

    auto unit = [&](int u, const bf16*& pA, const bf16*& pB) {
        int g = u * 32 + r;
        int m = g % 10, n = g / 10;
        pA = XeE + (size_t)(m * 256) * DIM;
        pB = WE + (size_t)(n * 128) * DIM;
    };
    auto epi = [&](int u, f32x4 (&acc)[8][4]) {
        int g = u * 32 + r;
        int m0 = (g % 10) * 256, n0f = (g / 10) * 128;
#pragma unroll
        for (int m = 0; m < 8; ++m)
#pragma unroll
            for (int cg = 0; cg < 2; ++cg)
#pragma unroll
                for (int j = 0; j < 4; ++j) {
                    float gg = acc[m][cg * 2 + 0][j];
                    float uu = acc[m][cg * 2 + 1][j];
                    float h = (gg / (1.f + __expf(-gg))) * uu;
                    int gr = m0 + wm * 128 + m * 16 + c16 * 4 + j;
                    int gc = n0f + wn * 32 + cg * 16 + r16;
                    hp[(size_t)gr * FF + gc] = (bf16)h;
                }
    };
    gemm256_persist<DIM / 64, DIM, DIM, 64, 16>(10, unit, epi, wave, lane);
}

// ---------------------------------------------------------------------------
// down (persistent): grid 256, e=b&7, r=b>>3. split-K=4: step u, block r ->
// mk = u*8 + (r&7) (m = mk>>2, kh = mk&3), n = r>>3. Exactly 5 units/block.
// bf16 partials into eo slice kh.
// B col decomposition validated r7/r8: col = wnl*64 + nlow*16 + r16l (+n0).
// ---------------------------------------------------------------------------
__global__ __launch_bounds__(512, 2) void down_kernel(const bf16* __restrict__ hbuf,
                                                      const bf16* __restrict__ Wd,
                                                      bf16* __restrict__ eo) {
    const int b = blockIdx.x;
    const int e = b & 7, r = b >> 3;
    const int tid = threadIdx.x, lane = tid & 63, wave = tid >> 6;
    const int wm = wave >> 2, wn = wave & 3;
    const int r16 = lane & 15, c16 = lane >> 4;

    const int l   = wave * 8 + (lane >> 3);
    const int csw = ((lane & 7) ^ (lane >> 3)) * 8;
    const int nlow = (l >> 4) & 1, wnl = l >> 5, r16l = l & 15;
    const bf16* hb  = hbuf + (size_t)e * CAP * FF + (size_t)l * FF + csw;
    const bf16* WdE = Wd + (size_t)e * DIM * FF
                    + (size_t)(wnl * 64 + nlow * 16 + r16l) * FF + csw;
    bf16* eoE = eo + (size_t)e * CAP * DIM;

    auto unit = [&](int u, const bf16*& pA, const bf16*& pB) {
        int mk = u * 8 + (r & 7);          // (m,kh), 0..39
        int n  = r >> 3;                   // 0..3
        int m = mk >> 2, kh = mk & 3;
        pA = hb + (size_t)(m * 256) * FF + kh * (FF / 4);
        pB = WdE + (size_t)(n * 256) * FF + kh * (FF / 4);
    };
    auto epi = [&](int u, f32x4 (&acc)[8][4]) {
        int mk = u * 8 + (r & 7);
        int m0 = (mk >> 2) * 256, kh = mk & 3;
        int n0 = (r >> 3) * 256;
        bf16* op = eoE + (size_t)kh * EOSL;
#pragma unroll
        for (int m = 0; m < 8; ++m)
#pragma unroll
            for (int nf = 0; nf < 4; ++nf)
#pragma unroll
                for (int j = 0; j < 4; ++j) {
                    int gr = m0 + wm * 128 + m * 16 + c16 * 4 + j;
                    int gc = n0 + wn * 64 + nf * 16 + r16;
                    op[(size_t)gr * DIM + gc] = (bf16)acc[m][nf][j];
                }
    };
    gemm256_persist<(FF / 4) / 64, FF, FF, 128, 32>(5, unit, epi, wave, lane);
}

// ---------------------------------------------------------------------------
// Combine: out[t] = sum_s w_ts * acc_ts * sum_{kh<4} eo[kh][dest_ts].
// ---------------------------------------------------------------------------
__global__ __launch_bounds__(256) void combine_kernel(const bf16* __restrict__ eo,
                                                      const int* __restrict__ dest,
                                                      const int* __restrict__ accf,
                                                      const float* __restrict__ topw,
                                                      float* __restrict__ out) {
    int t = blockIdx.x;
    float w0 = accf[t] ? topw[t * 2 + 0] : 0.f;           // slot 0: j = t
    float w1 = accf[N_TOK + t] ? topw[t * 2 + 1] : 0.f;   // slot 1: j = N + t
    const bf16* a0 = eo + (size_t)dest[t] * DIM;
    const bf16* b0 = eo + (size_t)dest[N_TOK + t] * DIM;
    int d = threadIdx.x * 4;
    float ax = 0, ay = 0, az = 0, aw = 0, bx = 0, by = 0, bz = 0, bw = 0;
#pragma unroll
    for (int s4 = 0; s4 < 4; ++s4) {
        bf16x4v a = *(const bf16x4v*)(a0 + (size_t)s4 * EOSL + d);
        bf16x4v bb = *(const bf16x4v*)(b0 + (size_t)s4 * EOSL + d);
        ax += (float)a[0]; ay += (float)a[1]; az += (float)a[2]; aw += (float)a[3];
        bx += (float)bb[0]; by += (float)bb[1]; bz += (float)bb[2]; bw += (float)bb[3];
    }
    float4 o;
    o.x = w0 * ax + w1 * bx;
    o.y = w0 * ay + w1 * by;
    o.z = w0 * az + w1 * bz;
    o.w = w0 * aw + w1 * bw;
    *(float4*)(out + (size_t)t * DIM + d) = o;
}

// ---------------------------------------------------------------------------
// Aux loss: deterministic fixed-tree reduction of probs mean + counts.
// ---------------------------------------------------------------------------
__global__ __launch_bounds__(256) void aux_kernel(const float* __restrict__ probs,
                                                  const int* __restrict__ counts,
                                                  float* __restrict__ out_aux) {
    __shared__ float sm[256][NEXP];
    float loc[NEXP];
#pragma unroll
    for (int e = 0; e < NEXP; ++e) loc[e] = 0.f;
    for (int t = threadIdx.x; t < N_TOK; t += 256)
#pragma unroll
        for (int e = 0; e < NEXP; ++e) loc[e] += probs[t * NEXP + e];
#pragma unroll
    for (int e = 0; e < NEXP; ++e) sm[threadIdx.x][e] = loc[e];
    __syncthreads();
    for (int s = 128; s > 0; s >>= 1) {
        if (threadIdx.x < s)
#pragma unroll
            for (int e = 0; e < NEXP; ++e) sm[threadIdx.x][e] += sm[threadIdx.x + s][e];
        __syncthreads();
    }
    if (threadIdx.x == 0) {
        int tot = 0;
        for (int e = 0; e < NEXP; ++e) tot += counts[e];
        float totf = tot > 0 ? (float)tot : 1.f;
        float aux = 0.f;
        for (int e = 0; e < NEXP; ++e)
            aux += ((float)counts[e] / totf) * (sm[0][e] / (float)N_TOK);
        out_aux[0] = 0.01f * (float)NEXP * aux;
    }
}

// ---------------------------------------------------------------------------
extern "C" void kernel_launch(void* const* d_in, const int* in_sizes, int n_in,
                              void* d_out, int out_size, void* d_ws, size_t ws_size,
                              hipStream_t stream) {
    const float* x  = (const float*)d_in[0];
    const float* Wr = (const float*)d_in[1];
    const float* Wg = (const float*)d_in[2];
    const float* Wu = (const float*)d_in[3];
    const float* Wd = (const float*)d_in[4];
    float* out = (float*)d_out;

    char* ws = (char*)d_ws;
    size_t off = 0;
    auto alloc = [&](size_t bytes) -> void* {
        void* p = ws + off;
        off += (bytes + 255) & ~(size_t)255;
        return p;
    };
    const size_t NW = (size_t)NEXP * FF * DIM;
    // Layout: Wd_bf FIRST so eo (4 bf16 split-K slices, 167.8 MB) can alias
    // Wg_bf+Wu_bf+Xe (176.2 MB) -- all three are dead once gateup completes,
    // and cvt/gather rewrite them on every call (replay-safe).
    bf16*  Wd_bf = (bf16*)alloc(NW * sizeof(bf16));
    bf16*  Wg_bf = (bf16*)alloc(NW * sizeof(bf16));
    bf16*  Wu_bf = (bf16*)alloc(NW * sizeof(bf16));
    bf16*  Xe    = (bf16*)alloc((size_t)NEXP * CAP * DIM * sizeof(bf16));
    bf16*  hbuf  = (bf16*)alloc((size_t)NEXP * CAP * FF * sizeof(bf16));
    float* probs = (float*)alloc((size_t)N_TOK * NEXP * sizeof(float));
    int*   topi  = (int*)alloc((size_t)N_TOK * 2 * sizeof(int));
    float* topw  = (float*)alloc((size_t)N_TOK * 2 * sizeof(float));
    int*   dst   = (int*)alloc((size_t)NASSIGN * sizeof(int));
    int*   accf  = (int*)alloc((size_t)NASSIGN * sizeof(int));
    int*   cnts  = (int*)alloc(NEXP * sizeof(int));
    bf16*  eo    = Wg_bf;   // alias (see above): 4*EOSL*2B <= Wg+Wu+Xe bytes

    cvt3_bf16_kernel<<<dim3(1024, 3), 256, 0, stream>>>(Wg, Wu, Wd, Wg_bf, Wu_bf, Wd_bf, (int)NW);
    router_kernel<<<N_TOK / 4, 256, 0, stream>>>(x, Wr, probs, topi, topw);
    rank_kernel<<<NEXP, 64, 0, stream>>>(topi, dst, accf, cnts);
    gather_kernel<<<NASSIGN, 256, 0, stream>>>(x, dst, accf, Xe);
    gateup_kernel<<<256, 512, 0, stream>>>(Xe, Wg_bf, Wu_bf, hbuf);
    down_kernel<<<256, 512, 0, stream>>>(hbuf, Wd_bf, eo);
    combine_kernel<<<N_TOK, 256, 0, stream>>>(eo, dst, accf, topw, out);
    aux_kernel<<<1, 256, 0, stream>>>(probs, cnts, out + (size_t)N_TOK * DIM);
}